// Round 1
// baseline (150.867 us; speedup 1.0000x reference)
//
#include <hip/hip_runtime.h>

typedef _Float16 h8  __attribute__((ext_vector_type(8)));
typedef _Float16 h2  __attribute__((ext_vector_type(2)));
typedef float f32x16 __attribute__((ext_vector_type(16)));

#define L2E 1.4426950408889634f

__device__ __forceinline__ void gll16(const void* g, void* l) {
  __builtin_amdgcn_global_load_lds((const __attribute__((address_space(1))) void*)g,
                                   (__attribute__((address_space(3))) void*)l, 16, 0, 0);
}

// ---------------- kernel 0: x (f32) -> xh (f16) ----------------
__global__ void k_cvt_x(const float* __restrict__ x, _Float16* __restrict__ xh) {
  int i = (blockIdx.x * 256 + threadIdx.x) * 8;
  float4 a = *(const float4*)(x + i);
  float4 b = *(const float4*)(x + i + 4);
  h8 o;
  o[0] = (_Float16)a.x; o[1] = (_Float16)a.y; o[2] = (_Float16)a.z; o[3] = (_Float16)a.w;
  o[4] = (_Float16)b.x; o[5] = (_Float16)b.y; o[6] = (_Float16)b.z; o[7] = (_Float16)b.w;
  *(h8*)(xh + i) = o;
}

// ---------------- kernel 0b: W (1024x128 f32) -> WT (3x128x1024 f16) ------
__global__ void k_cvt_w(const float* __restrict__ Wq, const float* __restrict__ Wk,
                        const float* __restrict__ Wv, _Float16* __restrict__ WT) {
  int id = blockIdx.x * 256 + threadIdx.x;     // 0 .. 3*131072-1
  int mat = id >> 17;
  int rem = id & 131071;
  int k = rem >> 7;
  int c = rem & 127;
  const float* W = (mat == 0) ? Wq : ((mat == 1) ? Wk : Wv);
  WT[mat * 131072 + c * 1024 + k] = (_Float16)W[rem];
}

// ---------------- kernel 1: QKV projection + rotary + gate ----------------
// grid = 128 row-tiles * 3 matrices; 256 threads (4 waves of 2x2 over 128x128)
__global__ __launch_bounds__(256, 2) void k_proj(
    const _Float16* __restrict__ xh,   // [16384][1024]
    const _Float16* __restrict__ WT,   // [3][128][1024]
    const float* __restrict__ cosT, const float* __restrict__ sinT,  // [4096][64]
    const float* __restrict__ gamma,
    _Float16* __restrict__ Qh, _Float16* __restrict__ Kh, _Float16* __restrict__ Vh) {
  __shared__ __align__(16) unsigned char lds[65536];  // [2 phase][x 16KB | w 16KB]
  const int tid = threadIdx.x;
  const int rt  = blockIdx.x & 127;
  const int mat = blockIdx.x >> 7;
  const int w = tid >> 6, lane = tid & 63;
  const int wr = w >> 1, wc = w & 1;
  const int r32 = lane & 31, h = lane >> 5;
  const int row0 = rt * 128;
  const _Float16* Wbase = WT + mat * 131072;

  auto stage = [&](int j) {
    int k0 = j * 64;
    unsigned char* xb = lds + (j & 1) * 32768;
    unsigned char* wb = xb + 16384;
#pragma unroll
    for (int ii = 0; ii < 4; ++ii) {
      int off = ii * 4096 + tid * 16;
      int r = off >> 7;            // row in tile (128B rows)
      int c = (off >> 4) & 7;      // 16B chunk slot
      gll16(xh + (size_t)(row0 + r) * 1024 + k0 + ((c ^ (r & 7)) * 8), xb + off);
    }
#pragma unroll
    for (int ii = 0; ii < 4; ++ii) {
      int off = ii * 4096 + tid * 16;
      int r = off >> 7;
      int c = (off >> 4) & 7;
      gll16(Wbase + (size_t)r * 1024 + k0 + ((c ^ (r & 7)) * 8), wb + off);
    }
  };

  f32x16 acc[2][2];
#pragma unroll
  for (int a_ = 0; a_ < 2; ++a_)
#pragma unroll
    for (int b_ = 0; b_ < 2; ++b_)
#pragma unroll
      for (int r = 0; r < 16; ++r) acc[a_][b_][r] = 0.f;

  stage(0);
  for (int j = 0; j < 16; ++j) {
    if (j < 15) {
      stage(j + 1);
      asm volatile("s_waitcnt vmcnt(8)\n\ts_barrier" ::: "memory");
    } else {
      asm volatile("s_waitcnt vmcnt(0)\n\ts_barrier" ::: "memory");
    }
    const _Float16* xt = (const _Float16*)(lds + (j & 1) * 32768);
    const _Float16* wt = xt + 8192;
#pragma unroll
    for (int kk = 0; kk < 4; ++kk) {
      h8 a0, a1, b0, b1;
      { int r = wr * 64 + r32;      a0 = *(const h8*)(xt + r * 64 + (((kk * 2 + h) ^ (r & 7)) * 8)); }
      { int r = wr * 64 + 32 + r32; a1 = *(const h8*)(xt + r * 64 + (((kk * 2 + h) ^ (r & 7)) * 8)); }
      { int r = wc * 64 + r32;      b0 = *(const h8*)(wt + r * 64 + (((kk * 2 + h) ^ (r & 7)) * 8)); }
      { int r = wc * 64 + 32 + r32; b1 = *(const h8*)(wt + r * 64 + (((kk * 2 + h) ^ (r & 7)) * 8)); }
      acc[0][0] = __builtin_amdgcn_mfma_f32_32x32x16_f16(a0, b0, acc[0][0], 0, 0, 0);
      acc[0][1] = __builtin_amdgcn_mfma_f32_32x32x16_f16(a0, b1, acc[0][1], 0, 0, 0);
      acc[1][0] = __builtin_amdgcn_mfma_f32_32x32x16_f16(a1, b0, acc[1][0], 0, 0, 0);
      acc[1][1] = __builtin_amdgcn_mfma_f32_32x32x16_f16(a1, b1, acc[1][1], 0, 0, 0);
    }
    asm volatile("s_waitcnt lgkmcnt(0)\n\ts_barrier" ::: "memory");
  }

  _Float16* dst = (mat == 0) ? Qh : ((mat == 1) ? Kh : Vh);
#pragma unroll
  for (int mt = 0; mt < 2; ++mt)
#pragma unroll
    for (int nt = 0; nt < 2; ++nt) {
      int col = wc * 64 + nt * 32 + r32;
      f32x16 c = acc[mt][nt];
      if (mat < 2) {
        float ge = expf(gamma[col]);
        float sc = (mat == 0) ? ge * 0.08838834764831845f : ge;  // fold 1/sqrt(128) into Q
        int i2 = col >> 1;
#pragma unroll
        for (int rg = 0; rg < 16; ++rg) {
          int row = row0 + wr * 64 + mt * 32 + (rg & 3) + 8 * (rg >> 2) + 4 * h;
          int pos = row & 4095;
          float cv = cosT[pos * 64 + i2], sv = sinT[pos * 64 + i2];
          float val = c[rg];
          float ot = __shfl_xor(val, 1);
          // even d: t1*cos - t2*sin ; odd d: t1*sin + t2*cos
          float rr = (lane & 1) ? fmaf(val, cv, ot * sv) : fmaf(val, cv, -ot * sv);
          dst[(size_t)row * 128 + col] = (_Float16)(rr * sc);
        }
      } else {
#pragma unroll
        for (int rg = 0; rg < 16; ++rg) {
          int row = row0 + wr * 64 + mt * 32 + (rg & 3) + 8 * (rg >> 2) + 4 * h;
          dst[(size_t)row * 128 + col] = (_Float16)c[rg];
        }
      }
    }
}

// ---------------- kernel 2: V [16384][128] -> VT [128][16384] ----------------
__global__ void k_trV(const _Float16* __restrict__ Vh, _Float16* __restrict__ VT) {
  __shared__ __align__(16) _Float16 tile[64 * 136];
  const int tid = threadIdx.x;
  const int kv0 = blockIdx.x * 64;
#pragma unroll
  for (int j = 0; j < 4; ++j) {
    int off = j * 4096 + tid * 16;   // bytes
    int r = off >> 8;                // 0..63
    int cb = (off >> 4) & 15;
    *(uint4*)((unsigned char*)tile + r * 272 + cb * 16) =
        *(const uint4*)((const unsigned char*)(Vh + (size_t)(kv0 + r) * 128) + cb * 16);
  }
  __syncthreads();
#pragma unroll
  for (int k = 0; k < 4; ++k) {
    int flat = k * 256 + tid;
    int d = flat >> 3, ch = flat & 7;
    union { unsigned short s[8]; uint4 v; } tmp;
#pragma unroll
    for (int jj = 0; jj < 8; ++jj)
      tmp.s[jj] = ((const unsigned short*)tile)[(ch * 8 + jj) * 136 + d];
    *(uint4*)(VT + (size_t)d * 16384 + kv0 + ch * 8) = tmp.v;
  }
}

// ---------------- kernel 3: flash attention ----------------
// grid = B*64 blocks, 256 threads = 4 waves: (wk = kv stream 0/1, wq = q tile 0/1)
__global__ __launch_bounds__(256, 1) void k_attn(
    const _Float16* __restrict__ Qh, const _Float16* __restrict__ Kh,
    const _Float16* __restrict__ VT, float* __restrict__ out) {
  __shared__ __align__(16) unsigned char lds_raw[65536];
  const int tid = threadIdx.x;
  const int b  = blockIdx.x >> 6;
  const int q0 = (blockIdx.x & 63) * 64;
  const int w = tid >> 6, lane = tid & 63;
  const int wk = w >> 1, wq = w & 1;     // threads 0..127 are wk==0 (stage stream 0)
  const int r32 = lane & 31, h = lane >> 5;

  // Q fragments in registers (B-operand of swapped QK^T)
  const _Float16* qrow = Qh + (size_t)(b * 4096 + q0 + wq * 32 + r32) * 128;
  h8 qf[8];
#pragma unroll
  for (int kk = 0; kk < 8; ++kk) qf[kk] = *(const h8*)(qrow + kk * 16 + h * 8);

  f32x16 o_acc[4];
#pragma unroll
  for (int dt = 0; dt < 4; ++dt)
#pragma unroll
    for (int r = 0; r < 16; ++r) o_acc[dt][r] = 0.f;
  float mcur = -INFINITY, lsum = 0.f;

  auto stage = [&](int j) {
    int s = tid >> 7, tt = tid & 127;
    int kv0 = (2 * j + s) * 32;
    unsigned char* kb = lds_raw + (s * 2 + (j & 1)) * 8192;
    unsigned char* vb = kb + 32768;
    const _Float16* Ksrc = Kh + (size_t)(b * 4096 + kv0) * 128;
#pragma unroll
    for (int ii = 0; ii < 4; ++ii) {
      int off = ii * 2048 + tt * 16;
      int r = off >> 8;            // kv row in tile (256B rows)
      int c = (off >> 4) & 15;
      gll16(Ksrc + r * 128 + ((c ^ (r & 7)) * 8), kb + off);
    }
#pragma unroll
    for (int ii = 0; ii < 4; ++ii) {
      int off = ii * 2048 + tt * 16;
      int rd = off >> 6;           // d row in VT tile (64B rows)
      int c = (off >> 4) & 3;
      gll16(VT + (size_t)rd * 16384 + (b * 4096 + kv0) + ((c ^ (rd & 3)) * 8), vb + off);
    }
  };

  stage(0);
  for (int i = 0; i < 64; ++i) {
    if (i < 63) {
      stage(i + 1);
      asm volatile("s_waitcnt vmcnt(8)\n\ts_barrier" ::: "memory");
    } else {
      asm volatile("s_waitcnt vmcnt(0)\n\ts_barrier" ::: "memory");
    }
    const _Float16* Kt = (const _Float16*)(lds_raw + (wk * 2 + (i & 1)) * 8192);
    const _Float16* Vt = (const _Float16*)(lds_raw + 32768 + (wk * 2 + (i & 1)) * 8192);

    // S^T = K * Q^T  (C: col = q = lane&31, row = kv = (r&3)+8*(r>>2)+4h)
    f32x16 st0, st1;
#pragma unroll
    for (int r = 0; r < 16; ++r) { st0[r] = 0.f; st1[r] = 0.f; }
#pragma unroll
    for (int kk = 0; kk < 8; ++kk) {
      int slot = (kk * 2 + h) ^ (r32 & 7);
      h8 a = *(const h8*)(Kt + r32 * 128 + slot * 8);
      if (kk & 1) st1 = __builtin_amdgcn_mfma_f32_32x32x16_f16(a, qf[kk], st1, 0, 0, 0);
      else        st0 = __builtin_amdgcn_mfma_f32_32x32x16_f16(a, qf[kk], st0, 0, 0, 0);
    }
    f32x16 st = st0 + st1;

    // online softmax (per lane = one q row; partner half in lane^32)
    float pm = st[0];
#pragma unroll
    for (int r = 1; r < 16; ++r) pm = fmaxf(pm, st[r]);
    pm = fmaxf(pm, __shfl_xor(pm, 32));
    float mnew = fmaxf(mcur, pm);
    float fsc = exp2f((mcur - mnew) * L2E);
    float mn2 = mnew * L2E;
    float pv[16]; float ps = 0.f;
#pragma unroll
    for (int r = 0; r < 16; ++r) { pv[r] = exp2f(fmaf(st[r], L2E, -mn2)); ps += pv[r]; }
    ps += __shfl_xor(ps, 32);
    lsum = fmaf(lsum, fsc, ps);
    mcur = mnew;
#pragma unroll
    for (int dt = 0; dt < 4; ++dt) o_acc[dt] = o_acc[dt] * fsc;

    // pack P to half2 words; kv pair of word t (own half h): 8*(t>>1) + 4h + 2*(t&1)
    unsigned int wrd[8], owd[8];
#pragma unroll
    for (int t8 = 0; t8 < 8; ++t8) {
      h2 hp; hp[0] = (_Float16)pv[2 * t8]; hp[1] = (_Float16)pv[2 * t8 + 1];
      wrd[t8] = __builtin_bit_cast(unsigned int, hp);
    }
#pragma unroll
    for (int t8 = 0; t8 < 8; ++t8) owd[t8] = (unsigned int)__shfl_xor((int)wrd[t8], 32);
    const bool hb = (h != 0);
#pragma unroll
    for (int kvb = 0; kvb < 2; ++kvb) {
      union { unsigned int u[4]; h8 v; } pb;
      pb.u[0] = hb ? owd[4 * kvb + 2] : wrd[4 * kvb + 0];
      pb.u[1] = hb ? owd[4 * kvb + 3] : wrd[4 * kvb + 1];
      pb.u[2] = hb ? wrd[4 * kvb + 2] : owd[4 * kvb + 0];
      pb.u[3] = hb ? wrd[4 * kvb + 3] : owd[4 * kvb + 1];
#pragma unroll
      for (int dt = 0; dt < 4; ++dt) {
        int rowv = dt * 32 + r32;
        int slotv = (2 * kvb + h) ^ (r32 & 3);
        h8 av = *(const h8*)(Vt + rowv * 32 + slotv * 8);
        o_acc[dt] = __builtin_amdgcn_mfma_f32_32x32x16_f16(av, pb.v, o_acc[dt], 0, 0, 0);
      }
    }
    asm volatile("s_waitcnt lgkmcnt(0)\n\ts_barrier" ::: "memory");
  }

  // ---- merge the two kv streams, normalize, transpose, store ----
  __syncthreads();
  float* MB = (float*)lds_raw;               // [2 wq][4 dt][16 reg][64 lane]
  float* ML = (float*)(lds_raw + 32768);     // [2 wq][m 32 | l 32]
  if (wk == 1) {
#pragma unroll
    for (int dt = 0; dt < 4; ++dt)
#pragma unroll
      for (int rg = 0; rg < 16; ++rg)
        MB[((wq * 4 + dt) * 16 + rg) * 64 + lane] = o_acc[dt][rg];
    if (lane < 32) { ML[wq * 64 + lane] = mcur; ML[wq * 64 + 32 + lane] = lsum; }
  }
  __syncthreads();
  if (wk == 0) {
    float m1 = ML[wq * 64 + r32], l1 = ML[wq * 64 + 32 + r32];
    float ms = fmaxf(mcur, m1);
    float f0 = exp2f((mcur - ms) * L2E), f1 = exp2f((m1 - ms) * L2E);
    float inv = 1.0f / fmaf(lsum, f0, l1 * f1);
#pragma unroll
    for (int dt = 0; dt < 4; ++dt)
#pragma unroll
      for (int rg = 0; rg < 16; ++rg)
        o_acc[dt][rg] = (o_acc[dt][rg] * f0 + MB[((wq * 4 + dt) * 16 + rg) * 64 + lane] * f1) * inv;
  }
  __syncthreads();
  float* OT = (float*)lds_raw;               // [64 q][136]
  if (wk == 0) {
#pragma unroll
    for (int dt = 0; dt < 4; ++dt)
#pragma unroll
      for (int rg = 0; rg < 16; ++rg) {
        int d = dt * 32 + (rg & 3) + 8 * (rg >> 2) + 4 * h;
        OT[(wq * 32 + r32) * 136 + d] = o_acc[dt][rg];
      }
  }
  __syncthreads();
#pragma unroll
  for (int pi = 0; pi < 8; ++pi) {
    int idx = pi * 256 + tid;
    int qr = idx >> 5, c4 = idx & 31;
    float4 v = *(const float4*)&OT[qr * 136 + c4 * 4];
    *(float4*)(out + (size_t)(b * 4096 + q0 + qr) * 128 + c4 * 4) = v;
  }
}

// ---------------- launcher ----------------
extern "C" void kernel_launch(void* const* d_in, const int* in_sizes, int n_in,
                              void* d_out, int out_size, void* d_ws, size_t ws_size,
                              hipStream_t stream) {
  const float* x     = (const float*)d_in[0];
  const float* cosT  = (const float*)d_in[1];
  const float* sinT  = (const float*)d_in[2];
  const float* Wq    = (const float*)d_in[3];
  const float* Wk    = (const float*)d_in[4];
  const float* Wv    = (const float*)d_in[5];
  const float* gamma = (const float*)d_in[6];
  char* ws = (char*)d_ws;
  _Float16* xh = (_Float16*)(ws);                    // 33,554,432 B
  _Float16* WT = (_Float16*)(ws + 33554432);         //    786,432 B
  _Float16* Qh = (_Float16*)(ws + 34340864);         //  4,194,304 B
  _Float16* Kh = (_Float16*)(ws + 38535168);         //  4,194,304 B
  _Float16* Vh = (_Float16*)(ws + 42729472);         //  4,194,304 B
  _Float16* VT = (_Float16*)(ws + 46923776);         //  4,194,304 B
  float* out = (float*)d_out;

  hipLaunchKernelGGL(k_cvt_x, dim3(8192), dim3(256), 0, stream, x, xh);
  hipLaunchKernelGGL(k_cvt_w, dim3(1536), dim3(256), 0, stream, Wq, Wk, Wv, WT);
  hipLaunchKernelGGL(k_proj, dim3(384), dim3(256), 0, stream, xh, WT, cosT, sinT, gamma, Qh, Kh, Vh);
  hipLaunchKernelGGL(k_trV, dim3(256), dim3(256), 0, stream, Vh, VT);
  hipLaunchKernelGGL(k_attn, dim3(256), dim3(256), 0, stream, Qh, Kh, VT, out);
}

// Round 3
// 114.679 us; speedup vs baseline: 1.3156x; 1.3156x over previous
//
#include <hip/hip_runtime.h>

typedef _Float16 h8  __attribute__((ext_vector_type(8)));
typedef float f32x16 __attribute__((ext_vector_type(16)));

#define L2E 1.4426950408889634f

__device__ __forceinline__ void gll16(const void* g, void* l) {
  __builtin_amdgcn_global_load_lds((const __attribute__((address_space(1))) void*)g,
                                   (__attribute__((address_space(3))) void*)l, 16, 0, 0);
}

// ---------------- kernel 0: x (f32) -> xh (f16) ----------------
__global__ void k_cvt_x(const float* __restrict__ x, _Float16* __restrict__ xh) {
  int i = (blockIdx.x * 256 + threadIdx.x) * 8;
  float4 a = *(const float4*)(x + i);
  float4 b = *(const float4*)(x + i + 4);
  h8 o;
  o[0] = (_Float16)a.x; o[1] = (_Float16)a.y; o[2] = (_Float16)a.z; o[3] = (_Float16)a.w;
  o[4] = (_Float16)b.x; o[5] = (_Float16)b.y; o[6] = (_Float16)b.z; o[7] = (_Float16)b.w;
  *(h8*)(xh + i) = o;
}

// ---------------- kernel 0b: W (1024x128 f32) -> WT (3x128x1024 f16) ------
__global__ void k_cvt_w(const float* __restrict__ Wq, const float* __restrict__ Wk,
                        const float* __restrict__ Wv, _Float16* __restrict__ WT) {
  int id = blockIdx.x * 256 + threadIdx.x;     // 0 .. 3*131072-1
  int mat = id >> 17;
  int rem = id & 131071;
  int k = rem >> 7;
  int c = rem & 127;
  const float* W = (mat == 0) ? Wq : ((mat == 1) ? Wk : Wv);
  WT[mat * 131072 + c * 1024 + k] = (_Float16)W[rem];
}

// ---------------- kernel 1: QKV projection + rotary + gate ----------------
// grid = 128 row-tiles * 3 matrices; 256 threads (4 waves of 2x2 over 128x128)
// mat==2 (V) writes the transposed VT [128][16384] directly.
__global__ __launch_bounds__(256, 2) void k_proj(
    const _Float16* __restrict__ xh,   // [16384][1024]
    const _Float16* __restrict__ WT,   // [3][128][1024]
    const float* __restrict__ cosT, const float* __restrict__ sinT,  // [4096][64]
    const float* __restrict__ gamma,
    _Float16* __restrict__ Qh, _Float16* __restrict__ Kh, _Float16* __restrict__ VT) {
  __shared__ __align__(16) unsigned char lds[65536];  // [2 phase][x 16KB | w 16KB]
  const int tid = threadIdx.x;
  const int rt  = blockIdx.x & 127;
  const int mat = blockIdx.x >> 7;
  const int w = tid >> 6, lane = tid & 63;
  const int wr = w >> 1, wc = w & 1;
  const int r32 = lane & 31, h = lane >> 5;
  const int row0 = rt * 128;
  const _Float16* Wbase = WT + mat * 131072;

  auto stage = [&](int j) {
    int k0 = j * 64;
    unsigned char* xb = lds + (j & 1) * 32768;
    unsigned char* wb = xb + 16384;
#pragma unroll
    for (int ii = 0; ii < 4; ++ii) {
      int off = ii * 4096 + tid * 16;
      int r = off >> 7;            // row in tile (128B rows)
      int c = (off >> 4) & 7;      // 16B chunk slot
      gll16(xh + (size_t)(row0 + r) * 1024 + k0 + ((c ^ (r & 7)) * 8), xb + off);
    }
#pragma unroll
    for (int ii = 0; ii < 4; ++ii) {
      int off = ii * 4096 + tid * 16;
      int r = off >> 7;
      int c = (off >> 4) & 7;
      gll16(Wbase + (size_t)r * 1024 + k0 + ((c ^ (r & 7)) * 8), wb + off);
    }
  };

  f32x16 acc[2][2];
#pragma unroll
  for (int a_ = 0; a_ < 2; ++a_)
#pragma unroll
    for (int b_ = 0; b_ < 2; ++b_)
#pragma unroll
      for (int r = 0; r < 16; ++r) acc[a_][b_][r] = 0.f;

  stage(0);
  for (int j = 0; j < 16; ++j) {
    if (j < 15) {
      stage(j + 1);
      asm volatile("s_waitcnt vmcnt(8)\n\ts_barrier" ::: "memory");
    } else {
      asm volatile("s_waitcnt vmcnt(0)\n\ts_barrier" ::: "memory");
    }
    const _Float16* xt = (const _Float16*)(lds + (j & 1) * 32768);
    const _Float16* wt = xt + 8192;
#pragma unroll
    for (int kk = 0; kk < 4; ++kk) {
      h8 a0, a1, b0, b1;
      { int r = wr * 64 + r32;      a0 = *(const h8*)(xt + r * 64 + (((kk * 2 + h) ^ (r & 7)) * 8)); }
      { int r = wr * 64 + 32 + r32; a1 = *(const h8*)(xt + r * 64 + (((kk * 2 + h) ^ (r & 7)) * 8)); }
      { int r = wc * 64 + r32;      b0 = *(const h8*)(wt + r * 64 + (((kk * 2 + h) ^ (r & 7)) * 8)); }
      { int r = wc * 64 + 32 + r32; b1 = *(const h8*)(wt + r * 64 + (((kk * 2 + h) ^ (r & 7)) * 8)); }
      acc[0][0] = __builtin_amdgcn_mfma_f32_32x32x16_f16(a0, b0, acc[0][0], 0, 0, 0);
      acc[0][1] = __builtin_amdgcn_mfma_f32_32x32x16_f16(a0, b1, acc[0][1], 0, 0, 0);
      acc[1][0] = __builtin_amdgcn_mfma_f32_32x32x16_f16(a1, b0, acc[1][0], 0, 0, 0);
      acc[1][1] = __builtin_amdgcn_mfma_f32_32x32x16_f16(a1, b1, acc[1][1], 0, 0, 0);
    }
    asm volatile("s_waitcnt lgkmcnt(0)\n\ts_barrier" ::: "memory");
  }

#pragma unroll
  for (int mt = 0; mt < 2; ++mt)
#pragma unroll
    for (int nt = 0; nt < 2; ++nt) {
      int col = wc * 64 + nt * 32 + r32;
      f32x16 c = acc[mt][nt];
      if (mat < 2) {
        _Float16* dst = (mat == 0) ? Qh : Kh;
        float ge = expf(gamma[col]);
        float sc = (mat == 0) ? ge * 0.08838834764831845f : ge;  // fold 1/sqrt(128) into Q
        int i2 = col >> 1;
#pragma unroll
        for (int rg = 0; rg < 16; ++rg) {
          int row = row0 + wr * 64 + mt * 32 + (rg & 3) + 8 * (rg >> 2) + 4 * h;
          int pos = row & 4095;
          float cv = cosT[pos * 64 + i2], sv = sinT[pos * 64 + i2];
          float val = c[rg];
          float ot = __shfl_xor(val, 1);
          // even d: t1*cos - t2*sin ; odd d: t1*sin + t2*cos
          float rr = (lane & 1) ? fmaf(val, cv, ot * sv) : fmaf(val, cv, -ot * sv);
          dst[(size_t)row * 128 + col] = (_Float16)(rr * sc);
        }
      } else {
        // V: write transposed directly. C rows (rg&3) are consecutive kv rows.
#pragma unroll
        for (int g = 0; g < 4; ++g) {
          union { _Float16 hh[4]; uint2 u; } pk;
#pragma unroll
          for (int j2 = 0; j2 < 4; ++j2) pk.hh[j2] = (_Float16)c[g * 4 + j2];
          int row = row0 + wr * 64 + mt * 32 + 8 * g + 4 * h;  // multiple of 4
          *(uint2*)(VT + (size_t)col * 16384 + row) = pk.u;
        }
      }
    }
}

// ---------------- kernel 2: flash attention ----------------
// grid = B*64 blocks, 512 threads = 8 waves: wk = kv stream (0..3), wq = q tile (0/1)
// dynamic LDS 128 KiB: K region [0,64K): 8 bufs of 8KB (stream*2+phase);
//                      V region [64K,128K): same indexing.
__global__ __launch_bounds__(512, 2) void k_attn(
    const _Float16* __restrict__ Qh, const _Float16* __restrict__ Kh,
    const _Float16* __restrict__ VT, float* __restrict__ out) {
  extern __shared__ __align__(16) unsigned char lds_raw[];
  const int tid = threadIdx.x;
  const int b  = blockIdx.x >> 6;
  const int q0 = (blockIdx.x & 63) * 64;
  const int w = tid >> 6, lane = tid & 63;
  const int wk = w >> 1, wq = w & 1;
  const int r32 = lane & 31, h = lane >> 5;

  // Q fragments in registers (B-operand of swapped QK^T)
  const _Float16* qrow = Qh + (size_t)(b * 4096 + q0 + wq * 32 + r32) * 128;
  h8 qf[8];
#pragma unroll
  for (int kk = 0; kk < 8; ++kk) qf[kk] = *(const h8*)(qrow + kk * 16 + h * 8);

  f32x16 o_acc[4];
#pragma unroll
  for (int dt = 0; dt < 4; ++dt)
#pragma unroll
    for (int r = 0; r < 16; ++r) o_acc[dt][r] = 0.f;
  float mcur = -INFINITY, lsum = 0.f;

  // stage: thread-group s (=wk of waves 2s,2s+1) stages stream s's K and V tiles
  auto stage = [&](int j) {
    int s = tid >> 7, tt = tid & 127;
    int kv0g = b * 4096 + (4 * j + s) * 32;
    unsigned char* kb = lds_raw + (s * 2 + (j & 1)) * 8192;
    unsigned char* vb = lds_raw + 65536 + (s * 2 + (j & 1)) * 8192;
    const _Float16* Ksrc = Kh + (size_t)kv0g * 128;
#pragma unroll
    for (int ii = 0; ii < 4; ++ii) {
      int off = ii * 2048 + tt * 16;
      int r = off >> 8;            // kv row in tile (256B rows)
      int c = (off >> 4) & 15;
      gll16(Ksrc + r * 128 + ((c ^ (r & 7)) * 8), kb + off);
    }
#pragma unroll
    for (int ii = 0; ii < 4; ++ii) {
      int off = ii * 2048 + tt * 16;
      int row = off >> 7;          // 128B rows: d-pair
      int w8 = (off >> 4) & 7;
      int par = w8 >> 2, sl = w8 & 3;
      int d = row * 2 + par;
      int kvc = sl ^ (row & 3);
      gll16(VT + (size_t)d * 16384 + kv0g + kvc * 8, vb + off);
    }
  };

  stage(0);
  for (int i = 0; i < 32; ++i) {
    if (i < 31) {
      stage(i + 1);
      asm volatile("s_waitcnt vmcnt(8)\n\ts_barrier" ::: "memory");
    } else {
      asm volatile("s_waitcnt vmcnt(0)\n\ts_barrier" ::: "memory");
    }
    const _Float16* Kt = (const _Float16*)(lds_raw + (wk * 2 + (i & 1)) * 8192);
    const _Float16* Vt = (const _Float16*)(lds_raw + 65536 + (wk * 2 + (i & 1)) * 8192);

    // S^T = K * Q^T  (C: col = q = lane&31, row = kv = (r&3)+8*(r>>2)+4h)
    f32x16 st0, st1;
#pragma unroll
    for (int r = 0; r < 16; ++r) { st0[r] = 0.f; st1[r] = 0.f; }
    __builtin_amdgcn_s_setprio(1);
#pragma unroll
    for (int kk = 0; kk < 8; ++kk) {
      int slot = (kk * 2 + h) ^ (r32 & 7);
      h8 a = *(const h8*)(Kt + r32 * 128 + slot * 8);
      if (kk & 1) st1 = __builtin_amdgcn_mfma_f32_32x32x16_f16(a, qf[kk], st1, 0, 0, 0);
      else        st0 = __builtin_amdgcn_mfma_f32_32x32x16_f16(a, qf[kk], st0, 0, 0, 0);
    }
    __builtin_amdgcn_s_setprio(0);
    f32x16 st = st0 + st1;

    // online softmax (per lane = one q row; partner half in lane^32)
    float pm = fmaxf(fmaxf(fmaxf(st[0], st[1]), fmaxf(st[2], st[3])),
                     fmaxf(fmaxf(st[4], st[5]), fmaxf(st[6], st[7])));
    float pm2 = fmaxf(fmaxf(fmaxf(st[8], st[9]), fmaxf(st[10], st[11])),
                      fmaxf(fmaxf(st[12], st[13]), fmaxf(st[14], st[15])));
    pm = fmaxf(pm, pm2);
    pm = fmaxf(pm, __shfl_xor(pm, 32));
    // defer-max: only rescale when the running max grew by > 8
    if (!__all(pm - mcur <= 8.0f)) {
      float mnew = fmaxf(mcur, pm);
      float fsc = exp2f((mcur - mnew) * L2E);
      lsum *= fsc;
#pragma unroll
      for (int dt = 0; dt < 4; ++dt) o_acc[dt] = o_acc[dt] * fsc;
      mcur = mnew;
    }
    float mn2 = mcur * L2E;
    float pv[16]; float ps = 0.f;
#pragma unroll
    for (int r = 0; r < 16; ++r) { pv[r] = exp2f(fmaf(st[r], L2E, -mn2)); ps += pv[r]; }
    ps += __shfl_xor(ps, 32);
    lsum += ps;

    // pack P to half2 words; kv pair of word t (own half h): 8*(t>>1) + 4h + 2*(t&1)
    unsigned int wrd[8], owd[8];
#pragma unroll
    for (int t8 = 0; t8 < 8; ++t8) {
      auto hp = __builtin_amdgcn_cvt_pkrtz(pv[2 * t8], pv[2 * t8 + 1]);
      wrd[t8] = __builtin_bit_cast(unsigned int, hp);
    }
#pragma unroll
    for (int t8 = 0; t8 < 8; ++t8) owd[t8] = (unsigned int)__shfl_xor((int)wrd[t8], 32);
    const bool hb = (h != 0);
    __builtin_amdgcn_s_setprio(1);
#pragma unroll
    for (int kvb = 0; kvb < 2; ++kvb) {
      union { unsigned int u[4]; h8 v; } pb;
      pb.u[0] = hb ? owd[4 * kvb + 2] : wrd[4 * kvb + 0];
      pb.u[1] = hb ? owd[4 * kvb + 3] : wrd[4 * kvb + 1];
      pb.u[2] = hb ? wrd[4 * kvb + 2] : owd[4 * kvb + 0];
      pb.u[3] = hb ? wrd[4 * kvb + 3] : owd[4 * kvb + 1];
#pragma unroll
      for (int dt = 0; dt < 4; ++dt) {
        int lrow = dt * 16 + (r32 >> 1);                 // 128B row (d-pair)
        int sl = (kvb * 2 + h) ^ (lrow & 3);
        h8 av = *(const h8*)(Vt + lrow * 64 + (r32 & 1) * 32 + sl * 8);
        o_acc[dt] = __builtin_amdgcn_mfma_f32_32x32x16_f16(av, pb.v, o_acc[dt], 0, 0, 0);
      }
    }
    __builtin_amdgcn_s_setprio(0);
    asm volatile("s_waitcnt lgkmcnt(0)\n\ts_barrier" ::: "memory");
  }

  // ---- merge the 4 kv streams, normalize, transpose, store ----
  __syncthreads();
  float* MB = (float*)lds_raw;                 // [3 si][2 wq][64 row][64 lane] floats
  float* ML = (float*)(lds_raw + 98304);       // [3 si][2 wq][m 32 | l 32]
  if (wk >= 1) {
    int si = wk - 1;
#pragma unroll
    for (int dt = 0; dt < 4; ++dt)
#pragma unroll
      for (int rg = 0; rg < 16; ++rg)
        MB[(((si * 2 + wq) * 64) + dt * 16 + rg) * 64 + lane] = o_acc[dt][rg];
    if (lane < 32) {
      ML[(si * 2 + wq) * 64 + lane] = mcur;
      ML[(si * 2 + wq) * 64 + 32 + lane] = lsum;
    }
  }
  __syncthreads();
  if (wk == 0) {
#pragma unroll
    for (int si = 0; si < 3; ++si) {
      float m1 = ML[(si * 2 + wq) * 64 + r32];
      float l1 = ML[(si * 2 + wq) * 64 + 32 + r32];
      float ms = fmaxf(mcur, m1);
      float f0 = exp2f((mcur - ms) * L2E), f1 = exp2f((m1 - ms) * L2E);
#pragma unroll
      for (int dt = 0; dt < 4; ++dt)
#pragma unroll
        for (int rg = 0; rg < 16; ++rg)
          o_acc[dt][rg] = o_acc[dt][rg] * f0 +
                          MB[(((si * 2 + wq) * 64) + dt * 16 + rg) * 64 + lane] * f1;
      lsum = lsum * f0 + l1 * f1;
      mcur = ms;
    }
    float inv = 1.0f / lsum;
#pragma unroll
    for (int dt = 0; dt < 4; ++dt) o_acc[dt] = o_acc[dt] * inv;
  }
  __syncthreads();
  float* OT = (float*)lds_raw;                 // [64 q][136]
  if (wk == 0) {
#pragma unroll
    for (int dt = 0; dt < 4; ++dt)
#pragma unroll
      for (int rg = 0; rg < 16; ++rg) {
        int d = dt * 32 + (rg & 3) + 8 * (rg >> 2) + 4 * h;
        OT[(wq * 32 + r32) * 136 + d] = o_acc[dt][rg];
      }
  }
  __syncthreads();
#pragma unroll
  for (int pi = 0; pi < 4; ++pi) {
    int idx = pi * 512 + tid;
    int qr = idx >> 5, c4 = idx & 31;
    float4 v = *(const float4*)&OT[qr * 136 + c4 * 4];
    *(float4*)(out + (size_t)(b * 4096 + q0 + qr) * 128 + c4 * 4) = v;
  }
}

// ---------------- launcher ----------------
extern "C" void kernel_launch(void* const* d_in, const int* in_sizes, int n_in,
                              void* d_out, int out_size, void* d_ws, size_t ws_size,
                              hipStream_t stream) {
  const float* x     = (const float*)d_in[0];
  const float* cosT  = (const float*)d_in[1];
  const float* sinT  = (const float*)d_in[2];
  const float* Wq    = (const float*)d_in[3];
  const float* Wk    = (const float*)d_in[4];
  const float* Wv    = (const float*)d_in[5];
  const float* gamma = (const float*)d_in[6];
  char* ws = (char*)d_ws;
  _Float16* xh = (_Float16*)(ws);                    // 33,554,432 B
  _Float16* WT = (_Float16*)(ws + 33554432);         //    786,432 B
  _Float16* Qh = (_Float16*)(ws + 34340864);         //  4,194,304 B
  _Float16* Kh = (_Float16*)(ws + 38535168);         //  4,194,304 B
  _Float16* VT = (_Float16*)(ws + 42729472);         //  4,194,304 B
  float* out = (float*)d_out;

  (void)hipFuncSetAttribute(reinterpret_cast<const void*>(k_attn),
                            hipFuncAttributeMaxDynamicSharedMemorySize, 131072);

  hipLaunchKernelGGL(k_cvt_x, dim3(8192), dim3(256), 0, stream, x, xh);
  hipLaunchKernelGGL(k_cvt_w, dim3(1536), dim3(256), 0, stream, Wq, Wk, Wv, WT);
  hipLaunchKernelGGL(k_proj, dim3(384), dim3(256), 0, stream, xh, WT, cosT, sinT, gamma, Qh, Kh, VT);
  hipLaunchKernelGGL(k_attn, dim3(256), dim3(512), 131072, stream, Qh, Kh, VT, out);
}

// Round 4
// 114.224 us; speedup vs baseline: 1.3208x; 1.0040x over previous
//
#include <hip/hip_runtime.h>

typedef _Float16 h8  __attribute__((ext_vector_type(8)));
typedef float f32x16 __attribute__((ext_vector_type(16)));

#define L2E 1.4426950408889634f

__device__ __forceinline__ void gll16(const void* g, void* l) {
  __builtin_amdgcn_global_load_lds((const __attribute__((address_space(1))) void*)g,
                                   (__attribute__((address_space(3))) void*)l, 16, 0, 0);
}

// ---------------- kernel 0: x (f32) -> xh (f16) ----------------
__global__ void k_cvt_x(const float* __restrict__ x, _Float16* __restrict__ xh) {
  int i = (blockIdx.x * 256 + threadIdx.x) * 8;
  float4 a = *(const float4*)(x + i);
  float4 b = *(const float4*)(x + i + 4);
  h8 o;
  o[0] = (_Float16)a.x; o[1] = (_Float16)a.y; o[2] = (_Float16)a.z; o[3] = (_Float16)a.w;
  o[4] = (_Float16)b.x; o[5] = (_Float16)b.y; o[6] = (_Float16)b.z; o[7] = (_Float16)b.w;
  *(h8*)(xh + i) = o;
}

// ---------------- kernel 0b: W (1024x128 f32) -> WT (3x128x1024 f16) ------
__global__ void k_cvt_w(const float* __restrict__ Wq, const float* __restrict__ Wk,
                        const float* __restrict__ Wv, _Float16* __restrict__ WT) {
  int id = blockIdx.x * 256 + threadIdx.x;     // 0 .. 3*131072-1
  int mat = id >> 17;
  int rem = id & 131071;
  int k = rem >> 7;
  int c = rem & 127;
  const float* W = (mat == 0) ? Wq : ((mat == 1) ? Wk : Wv);
  WT[mat * 131072 + c * 1024 + k] = (_Float16)W[rem];
}

// ---------------- kernel 1: QKV projection + rotary + gate ----------------
// grid = 128 row-tiles * 3 matrices; 256 threads (4 waves of 2x2 over 128x128)
// mat==2 (V) writes the transposed VT [128][16384] directly.
__global__ __launch_bounds__(256, 2) void k_proj(
    const _Float16* __restrict__ xh,   // [16384][1024]
    const _Float16* __restrict__ WT,   // [3][128][1024]
    const float* __restrict__ cosT, const float* __restrict__ sinT,  // [4096][64]
    const float* __restrict__ gamma,
    _Float16* __restrict__ Qh, _Float16* __restrict__ Kh, _Float16* __restrict__ VT) {
  __shared__ __align__(16) unsigned char lds[65536];  // [2 phase][x 16KB | w 16KB]
  const int tid = threadIdx.x;
  const int rt  = blockIdx.x & 127;
  const int mat = blockIdx.x >> 7;
  const int w = tid >> 6, lane = tid & 63;
  const int wr = w >> 1, wc = w & 1;
  const int r32 = lane & 31, h = lane >> 5;
  const int row0 = rt * 128;
  const _Float16* Wbase = WT + mat * 131072;

  auto stage = [&](int j) {
    int k0 = j * 64;
    unsigned char* xb = lds + (j & 1) * 32768;
    unsigned char* wb = xb + 16384;
#pragma unroll
    for (int ii = 0; ii < 4; ++ii) {
      int off = ii * 4096 + tid * 16;
      int r = off >> 7;            // row in tile (128B rows)
      int c = (off >> 4) & 7;      // 16B chunk slot
      gll16(xh + (size_t)(row0 + r) * 1024 + k0 + ((c ^ (r & 7)) * 8), xb + off);
    }
#pragma unroll
    for (int ii = 0; ii < 4; ++ii) {
      int off = ii * 4096 + tid * 16;
      int r = off >> 7;
      int c = (off >> 4) & 7;
      gll16(Wbase + (size_t)r * 1024 + k0 + ((c ^ (r & 7)) * 8), wb + off);
    }
  };

  f32x16 acc[2][2];
#pragma unroll
  for (int a_ = 0; a_ < 2; ++a_)
#pragma unroll
    for (int b_ = 0; b_ < 2; ++b_)
#pragma unroll
      for (int r = 0; r < 16; ++r) acc[a_][b_][r] = 0.f;

  stage(0);
  for (int j = 0; j < 16; ++j) {
    if (j < 15) {
      stage(j + 1);
      asm volatile("s_waitcnt vmcnt(8)\n\ts_barrier" ::: "memory");
    } else {
      asm volatile("s_waitcnt vmcnt(0)\n\ts_barrier" ::: "memory");
    }
    const _Float16* xt = (const _Float16*)(lds + (j & 1) * 32768);
    const _Float16* wt = xt + 8192;
#pragma unroll
    for (int kk = 0; kk < 4; ++kk) {
      h8 a0, a1, b0, b1;
      { int r = wr * 64 + r32;      a0 = *(const h8*)(xt + r * 64 + (((kk * 2 + h) ^ (r & 7)) * 8)); }
      { int r = wr * 64 + 32 + r32; a1 = *(const h8*)(xt + r * 64 + (((kk * 2 + h) ^ (r & 7)) * 8)); }
      { int r = wc * 64 + r32;      b0 = *(const h8*)(wt + r * 64 + (((kk * 2 + h) ^ (r & 7)) * 8)); }
      { int r = wc * 64 + 32 + r32; b1 = *(const h8*)(wt + r * 64 + (((kk * 2 + h) ^ (r & 7)) * 8)); }
      acc[0][0] = __builtin_amdgcn_mfma_f32_32x32x16_f16(a0, b0, acc[0][0], 0, 0, 0);
      acc[0][1] = __builtin_amdgcn_mfma_f32_32x32x16_f16(a0, b1, acc[0][1], 0, 0, 0);
      acc[1][0] = __builtin_amdgcn_mfma_f32_32x32x16_f16(a1, b0, acc[1][0], 0, 0, 0);
      acc[1][1] = __builtin_amdgcn_mfma_f32_32x32x16_f16(a1, b1, acc[1][1], 0, 0, 0);
    }
    asm volatile("s_waitcnt lgkmcnt(0)\n\ts_barrier" ::: "memory");
  }

#pragma unroll
  for (int mt = 0; mt < 2; ++mt)
#pragma unroll
    for (int nt = 0; nt < 2; ++nt) {
      int col = wc * 64 + nt * 32 + r32;
      f32x16 c = acc[mt][nt];
      if (mat < 2) {
        _Float16* dst = (mat == 0) ? Qh : Kh;
        float ge = expf(gamma[col]);
        float sc = (mat == 0) ? ge * 0.08838834764831845f : ge;  // fold 1/sqrt(128) into Q
        int i2 = col >> 1;
#pragma unroll
        for (int rg = 0; rg < 16; ++rg) {
          int row = row0 + wr * 64 + mt * 32 + (rg & 3) + 8 * (rg >> 2) + 4 * h;
          int pos = row & 4095;
          float cv = cosT[pos * 64 + i2], sv = sinT[pos * 64 + i2];
          float val = c[rg];
          float ot = __shfl_xor(val, 1);
          // even d: t1*cos - t2*sin ; odd d: t1*sin + t2*cos
          float rr = (lane & 1) ? fmaf(val, cv, ot * sv) : fmaf(val, cv, -ot * sv);
          dst[(size_t)row * 128 + col] = (_Float16)(rr * sc);
        }
      } else {
        // V: write transposed directly. C rows (rg&3) are consecutive kv rows.
#pragma unroll
        for (int g = 0; g < 4; ++g) {
          union { _Float16 hh[4]; uint2 u; } pk;
#pragma unroll
          for (int j2 = 0; j2 < 4; ++j2) pk.hh[j2] = (_Float16)c[g * 4 + j2];
          int row = row0 + wr * 64 + mt * 32 + 8 * g + 4 * h;  // multiple of 4
          *(uint2*)(VT + (size_t)col * 16384 + row) = pk.u;
        }
      }
    }
}

// ---------------- kernel 2: flash attention ----------------
// grid = B*64 blocks, 512 threads = 8 waves: wk = kv stream (0..3), wq = q tile (0/1)
// dynamic LDS 128 KiB: K region [0,64K): 8 bufs of 8KB (stream*2+phase);
//                      V region [64K,128K): same indexing.
// XCD swizzle: batch b -> XCDs {2b,2b+1}; KV (2MB/batch) then L2-resident.
__global__ __launch_bounds__(512, 2) void k_attn(
    const _Float16* __restrict__ Qh, const _Float16* __restrict__ Kh,
    const _Float16* __restrict__ VT, float* __restrict__ out) {
  extern __shared__ __align__(16) unsigned char lds_raw[];
  const int tid = threadIdx.x;
  const int bid = blockIdx.x;
  const int xcd = bid & 7;
  const int b  = xcd >> 1;
  const int q0 = ((xcd & 1) + 2 * (bid >> 3)) * 64;
  const int w = tid >> 6, lane = tid & 63;
  const int wk = w >> 1, wq = w & 1;
  const int r32 = lane & 31, h = lane >> 5;

  // Q fragments in registers (B-operand of swapped QK^T)
  const _Float16* qrow = Qh + (size_t)(b * 4096 + q0 + wq * 32 + r32) * 128;
  h8 qf[8];
#pragma unroll
  for (int kk = 0; kk < 8; ++kk) qf[kk] = *(const h8*)(qrow + kk * 16 + h * 8);

  f32x16 o_acc[4];
#pragma unroll
  for (int dt = 0; dt < 4; ++dt)
#pragma unroll
    for (int r = 0; r < 16; ++r) o_acc[dt][r] = 0.f;
  float mcur = -INFINITY, lsum = 0.f;

  // stage: thread-group s (=wk of waves 2s,2s+1) stages stream s's K and V tiles
  auto stage = [&](int j) {
    int s = tid >> 7, tt = tid & 127;
    int kv0g = b * 4096 + (4 * j + s) * 32;
    unsigned char* kb = lds_raw + (s * 2 + (j & 1)) * 8192;
    unsigned char* vb = lds_raw + 65536 + (s * 2 + (j & 1)) * 8192;
    const _Float16* Ksrc = Kh + (size_t)kv0g * 128;
#pragma unroll
    for (int ii = 0; ii < 4; ++ii) {
      int off = ii * 2048 + tt * 16;
      int r = off >> 8;            // kv row in tile (256B rows)
      int c = (off >> 4) & 15;
      gll16(Ksrc + r * 128 + ((c ^ (r & 7)) * 8), kb + off);
    }
#pragma unroll
    for (int ii = 0; ii < 4; ++ii) {
      int off = ii * 2048 + tt * 16;
      int row = off >> 7;          // 128B rows: d-pair
      int w8 = (off >> 4) & 7;
      int par = w8 >> 2, sl = w8 & 3;
      int d = row * 2 + par;
      int kvc = sl ^ (row & 3);
      gll16(VT + (size_t)d * 16384 + kv0g + kvc * 8, vb + off);
    }
  };

  stage(0);
  for (int i = 0; i < 32; ++i) {
    if (i < 31) {
      stage(i + 1);
      asm volatile("s_waitcnt vmcnt(8)\n\ts_barrier" ::: "memory");
    } else {
      asm volatile("s_waitcnt vmcnt(0)\n\ts_barrier" ::: "memory");
    }
    const _Float16* Kt = (const _Float16*)(lds_raw + (wk * 2 + (i & 1)) * 8192);
    const _Float16* Vt = (const _Float16*)(lds_raw + 65536 + (wk * 2 + (i & 1)) * 8192);

    // S^T = K * Q^T  (C: col = q = lane&31, row = kv = (r&3)+8*(r>>2)+4h)
    f32x16 st0, st1;
#pragma unroll
    for (int r = 0; r < 16; ++r) { st0[r] = 0.f; st1[r] = 0.f; }
    __builtin_amdgcn_s_setprio(1);
#pragma unroll
    for (int kk = 0; kk < 8; ++kk) {
      int slot = (kk * 2 + h) ^ (r32 & 7);
      h8 a = *(const h8*)(Kt + r32 * 128 + slot * 8);
      if (kk & 1) st1 = __builtin_amdgcn_mfma_f32_32x32x16_f16(a, qf[kk], st1, 0, 0, 0);
      else        st0 = __builtin_amdgcn_mfma_f32_32x32x16_f16(a, qf[kk], st0, 0, 0, 0);
    }
    __builtin_amdgcn_s_setprio(0);
    f32x16 st = st0 + st1;

    // online softmax (per lane = one q row; partner half in lane^32)
    float pm = fmaxf(fmaxf(fmaxf(st[0], st[1]), fmaxf(st[2], st[3])),
                     fmaxf(fmaxf(st[4], st[5]), fmaxf(st[6], st[7])));
    float pm2 = fmaxf(fmaxf(fmaxf(st[8], st[9]), fmaxf(st[10], st[11])),
                      fmaxf(fmaxf(st[12], st[13]), fmaxf(st[14], st[15])));
    pm = fmaxf(pm, pm2);
    pm = fmaxf(pm, __shfl_xor(pm, 32));
    // defer-max: only rescale when the running max grew by > 8
    if (!__all(pm - mcur <= 8.0f)) {
      float mnew = fmaxf(mcur, pm);
      float fsc = exp2f((mcur - mnew) * L2E);
      lsum *= fsc;
#pragma unroll
      for (int dt = 0; dt < 4; ++dt) o_acc[dt] = o_acc[dt] * fsc;
      mcur = mnew;
    }
    float mn2 = mcur * L2E;
    float pv[16]; float ps = 0.f;
#pragma unroll
    for (int r = 0; r < 16; ++r) { pv[r] = exp2f(fmaf(st[r], L2E, -mn2)); ps += pv[r]; }
    ps += __shfl_xor(ps, 32);
    lsum += ps;

    // pack P to half2 words; kv pair of word t (own half h): 8*(t>>1) + 4h + 2*(t&1)
    unsigned int wrd[8], owd[8];
#pragma unroll
    for (int t8 = 0; t8 < 8; ++t8) {
      auto hp = __builtin_amdgcn_cvt_pkrtz(pv[2 * t8], pv[2 * t8 + 1]);
      wrd[t8] = __builtin_bit_cast(unsigned int, hp);
    }
#pragma unroll
    for (int t8 = 0; t8 < 8; ++t8) owd[t8] = (unsigned int)__shfl_xor((int)wrd[t8], 32);
    const bool hb = (h != 0);
    __builtin_amdgcn_s_setprio(1);
#pragma unroll
    for (int kvb = 0; kvb < 2; ++kvb) {
      union { unsigned int u[4]; h8 v; } pb;
      pb.u[0] = hb ? owd[4 * kvb + 2] : wrd[4 * kvb + 0];
      pb.u[1] = hb ? owd[4 * kvb + 3] : wrd[4 * kvb + 1];
      pb.u[2] = hb ? wrd[4 * kvb + 2] : owd[4 * kvb + 0];
      pb.u[3] = hb ? wrd[4 * kvb + 3] : owd[4 * kvb + 1];
#pragma unroll
      for (int dt = 0; dt < 4; ++dt) {
        int lrow = dt * 16 + (r32 >> 1);                 // 128B row (d-pair)
        int sl = (kvb * 2 + h) ^ (lrow & 3);
        h8 av = *(const h8*)(Vt + lrow * 64 + (r32 & 1) * 32 + sl * 8);
        o_acc[dt] = __builtin_amdgcn_mfma_f32_32x32x16_f16(av, pb.v, o_acc[dt], 0, 0, 0);
      }
    }
    __builtin_amdgcn_s_setprio(0);
    asm volatile("s_waitcnt lgkmcnt(0)\n\ts_barrier" ::: "memory");
  }

  // ---- merge the 4 kv streams, normalize, transpose, store ----
  __syncthreads();
  float* MB = (float*)lds_raw;                 // [3 si][2 wq][64 row][64 lane] floats
  float* ML = (float*)(lds_raw + 98304);       // [3 si][2 wq][m 32 | l 32]
  if (wk >= 1) {
    int si = wk - 1;
#pragma unroll
    for (int dt = 0; dt < 4; ++dt)
#pragma unroll
      for (int rg = 0; rg < 16; ++rg)
        MB[(((si * 2 + wq) * 64) + dt * 16 + rg) * 64 + lane] = o_acc[dt][rg];
    if (lane < 32) {
      ML[(si * 2 + wq) * 64 + lane] = mcur;
      ML[(si * 2 + wq) * 64 + 32 + lane] = lsum;
    }
  }
  __syncthreads();
  if (wk == 0) {
#pragma unroll
    for (int si = 0; si < 3; ++si) {
      float m1 = ML[(si * 2 + wq) * 64 + r32];
      float l1 = ML[(si * 2 + wq) * 64 + 32 + r32];
      float ms = fmaxf(mcur, m1);
      float f0 = exp2f((mcur - ms) * L2E), f1 = exp2f((m1 - ms) * L2E);
#pragma unroll
      for (int dt = 0; dt < 4; ++dt)
#pragma unroll
        for (int rg = 0; rg < 16; ++rg)
          o_acc[dt][rg] = o_acc[dt][rg] * f0 +
                          MB[(((si * 2 + wq) * 64) + dt * 16 + rg) * 64 + lane] * f1;
      lsum = lsum * f0 + l1 * f1;
      mcur = ms;
    }
    float inv = 1.0f / lsum;
#pragma unroll
    for (int dt = 0; dt < 4; ++dt) o_acc[dt] = o_acc[dt] * inv;
  }
  __syncthreads();
  float* OT = (float*)lds_raw;                 // [64 q][129] (stride 129: bank = (r32+d)%32)
  if (wk == 0) {
#pragma unroll
    for (int dt = 0; dt < 4; ++dt)
#pragma unroll
      for (int rg = 0; rg < 16; ++rg) {
        int d = dt * 32 + (rg & 3) + 8 * (rg >> 2) + 4 * h;
        OT[(wq * 32 + r32) * 129 + d] = o_acc[dt][rg];
      }
  }
  __syncthreads();
#pragma unroll
  for (int pi = 0; pi < 16; ++pi) {
    int idx = pi * 512 + tid;
    int qr = idx >> 7, c = idx & 127;
    out[(size_t)(b * 4096 + q0 + qr) * 128 + c] = OT[qr * 129 + c];
  }
}

// ---------------- launcher ----------------
extern "C" void kernel_launch(void* const* d_in, const int* in_sizes, int n_in,
                              void* d_out, int out_size, void* d_ws, size_t ws_size,
                              hipStream_t stream) {
  const float* x     = (const float*)d_in[0];
  const float* cosT  = (const float*)d_in[1];
  const float* sinT  = (const float*)d_in[2];
  const float* Wq    = (const float*)d_in[3];
  const float* Wk    = (const float*)d_in[4];
  const float* Wv    = (const float*)d_in[5];
  const float* gamma = (const float*)d_in[6];
  char* ws = (char*)d_ws;
  _Float16* xh = (_Float16*)(ws);                    // 33,554,432 B
  _Float16* WT = (_Float16*)(ws + 33554432);         //    786,432 B
  _Float16* Qh = (_Float16*)(ws + 34340864);         //  4,194,304 B
  _Float16* Kh = (_Float16*)(ws + 38535168);         //  4,194,304 B
  _Float16* VT = (_Float16*)(ws + 42729472);         //  4,194,304 B
  float* out = (float*)d_out;

  (void)hipFuncSetAttribute(reinterpret_cast<const void*>(k_attn),
                            hipFuncAttributeMaxDynamicSharedMemorySize, 131072);

  hipLaunchKernelGGL(k_cvt_x, dim3(8192), dim3(256), 0, stream, x, xh);
  hipLaunchKernelGGL(k_cvt_w, dim3(1536), dim3(256), 0, stream, Wq, Wk, Wv, WT);
  hipLaunchKernelGGL(k_proj, dim3(384), dim3(256), 0, stream, xh, WT, cosT, sinT, gamma, Qh, Kh, VT);
  hipLaunchKernelGGL(k_attn, dim3(256), dim3(512), 131072, stream, Qh, Kh, VT, out);
}

// Round 5
// 113.641 us; speedup vs baseline: 1.3276x; 1.0051x over previous
//
#include <hip/hip_runtime.h>

typedef _Float16 h8  __attribute__((ext_vector_type(8)));
typedef float f32x16 __attribute__((ext_vector_type(16)));

#define L2E 1.4426950408889634f

__device__ __forceinline__ void gll16(const void* g, void* l) {
  __builtin_amdgcn_global_load_lds((const __attribute__((address_space(1))) void*)g,
                                   (__attribute__((address_space(3))) void*)l, 16, 0, 0);
}

// ---------------- kernel 0: x (f32) -> xh (f16) ----------------
__global__ void k_cvt_x(const float* __restrict__ x, _Float16* __restrict__ xh) {
  int i = (blockIdx.x * 256 + threadIdx.x) * 8;
  float4 a = *(const float4*)(x + i);
  float4 b = *(const float4*)(x + i + 4);
  h8 o;
  o[0] = (_Float16)a.x; o[1] = (_Float16)a.y; o[2] = (_Float16)a.z; o[3] = (_Float16)a.w;
  o[4] = (_Float16)b.x; o[5] = (_Float16)b.y; o[6] = (_Float16)b.z; o[7] = (_Float16)b.w;
  *(h8*)(xh + i) = o;
}

// ---------------- kernel 0b: W (1024x128 f32) -> WT (3x128x1024 f16) ------
__global__ void k_cvt_w(const float* __restrict__ Wq, const float* __restrict__ Wk,
                        const float* __restrict__ Wv, _Float16* __restrict__ WT) {
  int id = blockIdx.x * 256 + threadIdx.x;     // 0 .. 3*131072-1
  int mat = id >> 17;
  int rem = id & 131071;
  int k = rem >> 7;
  int c = rem & 127;
  const float* W = (mat == 0) ? Wq : ((mat == 1) ? Wk : Wv);
  WT[mat * 131072 + c * 1024 + k] = (_Float16)W[rem];
}

// ---------------- kernel 1: QKV projection + rotary + gate ----------------
// grid = 128 row-tiles * 3 matrices; 256 threads (4 waves of 2x2 over 128x128)
// Q: row-major [16384][128].
// K: fragment-major for mfma_32x32x16 A-operand:
//    half-index = (kv>>5)*4096 + (d>>4)*512 + ((d>>3)&1)*256 + (kv&31)*8 + (d&7)
// V: fragment-major (A-operand of PV, rows = d, k-dim = kv):
//    half-index = (kv>>5)*4096 + ((d>>5)*2 + ((kv>>4)&1))*512 + ((kv>>3)&1)*256 + (d&31)*8 + (kv&7)
__global__ __launch_bounds__(256, 2) void k_proj(
    const _Float16* __restrict__ xh,   // [16384][1024]
    const _Float16* __restrict__ WT,   // [3][128][1024]
    const float* __restrict__ cosT, const float* __restrict__ sinT,  // [4096][64]
    const float* __restrict__ gamma,
    _Float16* __restrict__ Qh, _Float16* __restrict__ Kh, _Float16* __restrict__ VT) {
  __shared__ __align__(16) unsigned char lds[65536];  // [2 phase][x 16KB | w 16KB]
  const int tid = threadIdx.x;
  const int rt  = blockIdx.x & 127;
  const int mat = blockIdx.x >> 7;
  const int w = tid >> 6, lane = tid & 63;
  const int wr = w >> 1, wc = w & 1;
  const int r32 = lane & 31, h = lane >> 5;
  const int row0 = rt * 128;
  const _Float16* Wbase = WT + mat * 131072;

  auto stage = [&](int j) {
    int k0 = j * 64;
    unsigned char* xb = lds + (j & 1) * 32768;
    unsigned char* wb = xb + 16384;
#pragma unroll
    for (int ii = 0; ii < 4; ++ii) {
      int off = ii * 4096 + tid * 16;
      int r = off >> 7;            // row in tile (128B rows)
      int c = (off >> 4) & 7;      // 16B chunk slot
      gll16(xh + (size_t)(row0 + r) * 1024 + k0 + ((c ^ (r & 7)) * 8), xb + off);
    }
#pragma unroll
    for (int ii = 0; ii < 4; ++ii) {
      int off = ii * 4096 + tid * 16;
      int r = off >> 7;
      int c = (off >> 4) & 7;
      gll16(Wbase + (size_t)r * 1024 + k0 + ((c ^ (r & 7)) * 8), wb + off);
    }
  };

  f32x16 acc[2][2];
#pragma unroll
  for (int a_ = 0; a_ < 2; ++a_)
#pragma unroll
    for (int b_ = 0; b_ < 2; ++b_)
#pragma unroll
      for (int r = 0; r < 16; ++r) acc[a_][b_][r] = 0.f;

  stage(0);
  for (int j = 0; j < 16; ++j) {
    if (j < 15) {
      stage(j + 1);
      asm volatile("s_waitcnt vmcnt(8)\n\ts_barrier" ::: "memory");
    } else {
      asm volatile("s_waitcnt vmcnt(0)\n\ts_barrier" ::: "memory");
    }
    const _Float16* xt = (const _Float16*)(lds + (j & 1) * 32768);
    const _Float16* wt = xt + 8192;
#pragma unroll
    for (int kk = 0; kk < 4; ++kk) {
      h8 a0, a1, b0, b1;
      { int r = wr * 64 + r32;      a0 = *(const h8*)(xt + r * 64 + (((kk * 2 + h) ^ (r & 7)) * 8)); }
      { int r = wr * 64 + 32 + r32; a1 = *(const h8*)(xt + r * 64 + (((kk * 2 + h) ^ (r & 7)) * 8)); }
      { int r = wc * 64 + r32;      b0 = *(const h8*)(wt + r * 64 + (((kk * 2 + h) ^ (r & 7)) * 8)); }
      { int r = wc * 64 + 32 + r32; b1 = *(const h8*)(wt + r * 64 + (((kk * 2 + h) ^ (r & 7)) * 8)); }
      acc[0][0] = __builtin_amdgcn_mfma_f32_32x32x16_f16(a0, b0, acc[0][0], 0, 0, 0);
      acc[0][1] = __builtin_amdgcn_mfma_f32_32x32x16_f16(a0, b1, acc[0][1], 0, 0, 0);
      acc[1][0] = __builtin_amdgcn_mfma_f32_32x32x16_f16(a1, b0, acc[1][0], 0, 0, 0);
      acc[1][1] = __builtin_amdgcn_mfma_f32_32x32x16_f16(a1, b1, acc[1][1], 0, 0, 0);
    }
    asm volatile("s_waitcnt lgkmcnt(0)\n\ts_barrier" ::: "memory");
  }

#pragma unroll
  for (int mt = 0; mt < 2; ++mt)
#pragma unroll
    for (int nt = 0; nt < 2; ++nt) {
      int col = wc * 64 + nt * 32 + r32;
      f32x16 c = acc[mt][nt];
      if (mat < 2) {
        float ge = expf(gamma[col]);
        float sc = (mat == 0) ? ge * 0.08838834764831845f : ge;  // fold 1/sqrt(128) into Q
        int i2 = col >> 1;
#pragma unroll
        for (int rg = 0; rg < 16; ++rg) {
          int row = row0 + wr * 64 + mt * 32 + (rg & 3) + 8 * (rg >> 2) + 4 * h;
          int pos = row & 4095;
          float cv = cosT[pos * 64 + i2], sv = sinT[pos * 64 + i2];
          float val = c[rg];
          float ot = __shfl_xor(val, 1);
          // even d: t1*cos - t2*sin ; odd d: t1*sin + t2*cos
          float rr = (lane & 1) ? fmaf(val, cv, ot * sv) : fmaf(val, cv, -ot * sv);
          float v = rr * sc;
          if (mat == 0) {
            Qh[(size_t)row * 128 + col] = (_Float16)v;
          } else {
            size_t ka = (size_t)(row >> 5) * 4096 + (col >> 4) * 512 +
                        ((col >> 3) & 1) * 256 + (row & 31) * 8 + (col & 7);
            Kh[ka] = (_Float16)v;
          }
        }
      } else {
        // V fragment-major: rg group g covers 4 consecutive kv at fixed d=col.
#pragma unroll
        for (int g = 0; g < 4; ++g) {
          union { _Float16 hh[4]; uint2 u; } pk;
#pragma unroll
          for (int j2 = 0; j2 < 4; ++j2) pk.hh[j2] = (_Float16)c[g * 4 + j2];
          int kv = row0 + wr * 64 + mt * 32 + 8 * g + 4 * h;  // multiple of 4
          size_t va = (size_t)(kv >> 5) * 4096 +
                      ((col >> 5) * 2 + ((kv >> 4) & 1)) * 512 +
                      ((kv >> 3) & 1) * 256 + (col & 31) * 8 + (kv & 7);
          *(uint2*)(VT + va) = pk.u;
        }
      }
    }
}

// ---------------- kernel 2: flash attention (no-LDS main loop) ----------------
// grid = B*64 blocks, 512 threads = 8 waves: wk = kv stream (0..3), wq = q tile (0/1)
// K/V read directly from fragment-major global layouts into registers.
// LDS used only for the final stream merge. XCD swizzle keeps KV L2-resident.
__global__ __launch_bounds__(512, 2) void k_attn(
    const _Float16* __restrict__ Qh, const _Float16* __restrict__ Kh,
    const _Float16* __restrict__ VT, float* __restrict__ out) {
  extern __shared__ __align__(16) unsigned char lds_raw[];
  const int tid = threadIdx.x;
  const int bid = blockIdx.x;
  const int xcd = bid & 7;
  const int b  = xcd >> 1;
  const int q0 = ((xcd & 1) + 2 * (bid >> 3)) * 64;
  const int w = tid >> 6, lane = tid & 63;
  const int wk = w >> 1, wq = w & 1;
  const int r32 = lane & 31, h = lane >> 5;

  // Q fragments in registers (B-operand of swapped QK^T)
  const _Float16* qrow = Qh + (size_t)(b * 4096 + q0 + wq * 32 + r32) * 128;
  h8 qf[8];
#pragma unroll
  for (int kk = 0; kk < 8; ++kk) qf[kk] = *(const h8*)(qrow + kk * 16 + h * 8);

  // fragment bases for this wave's stream (tiles t = b*128 + 4*i + wk)
  const _Float16* Kfb = Kh + (size_t)(b * 128 + wk) * 4096 + lane * 8;
  const _Float16* Vfb = VT + (size_t)(b * 128 + wk) * 4096 + lane * 8;

  f32x16 o_acc[4];
#pragma unroll
  for (int dt = 0; dt < 4; ++dt)
#pragma unroll
    for (int r = 0; r < 16; ++r) o_acc[dt][r] = 0.f;
  float mcur = -INFINITY, lsum = 0.f;

  // preload K fragments for iter 0
  h8 kf[8];
#pragma unroll
  for (int kk = 0; kk < 8; ++kk) kf[kk] = *(const h8*)(Kfb + kk * 512);

  for (int i = 0; i < 32; ++i) {
    __builtin_amdgcn_s_barrier();   // pacing only (no shared data in loop)

    // V fragments for THIS tile: consumed after softmax (~300cy away)
    const _Float16* Vcur = Vfb + (size_t)i * 16384;
    h8 vf[8];
#pragma unroll
    for (int u = 0; u < 8; ++u) vf[u] = *(const h8*)(Vcur + u * 512);

    // QK^T consuming kf; roll-refill kf for tile i+1
    const _Float16* Knext = Kfb + (size_t)(i + 1) * 16384;
    f32x16 st0, st1;
#pragma unroll
    for (int r = 0; r < 16; ++r) { st0[r] = 0.f; st1[r] = 0.f; }
    __builtin_amdgcn_s_setprio(1);
#pragma unroll
    for (int kk = 0; kk < 8; ++kk) {
      h8 a = kf[kk];
      if (i < 31) kf[kk] = *(const h8*)(Knext + kk * 512);
      if (kk & 1) st1 = __builtin_amdgcn_mfma_f32_32x32x16_f16(a, qf[kk], st1, 0, 0, 0);
      else        st0 = __builtin_amdgcn_mfma_f32_32x32x16_f16(a, qf[kk], st0, 0, 0, 0);
    }
    __builtin_amdgcn_s_setprio(0);
    f32x16 st = st0 + st1;

    // online softmax (per lane = one q row; partner half in lane^32)
    float pm = fmaxf(fmaxf(fmaxf(st[0], st[1]), fmaxf(st[2], st[3])),
                     fmaxf(fmaxf(st[4], st[5]), fmaxf(st[6], st[7])));
    float pm2 = fmaxf(fmaxf(fmaxf(st[8], st[9]), fmaxf(st[10], st[11])),
                      fmaxf(fmaxf(st[12], st[13]), fmaxf(st[14], st[15])));
    pm = fmaxf(pm, pm2);
    pm = fmaxf(pm, __shfl_xor(pm, 32));
    // defer-max: only rescale when the running max grew by > 8
    if (!__all(pm - mcur <= 8.0f)) {
      float mnew = fmaxf(mcur, pm);
      float fsc = exp2f((mcur - mnew) * L2E);
      lsum *= fsc;
#pragma unroll
      for (int dt = 0; dt < 4; ++dt) o_acc[dt] = o_acc[dt] * fsc;
      mcur = mnew;
    }
    float mn2 = mcur * L2E;
    float pv[16]; float ps = 0.f;
#pragma unroll
    for (int r = 0; r < 16; ++r) { pv[r] = exp2f(fmaf(st[r], L2E, -mn2)); ps += pv[r]; }
    ps += __shfl_xor(ps, 32);
    lsum += ps;

    // pack P to half2 words; kv pair of word t (own half h): 8*(t>>1) + 4h + 2*(t&1)
    unsigned int wrd[8], owd[8];
#pragma unroll
    for (int t8 = 0; t8 < 8; ++t8) {
      auto hp = __builtin_amdgcn_cvt_pkrtz(pv[2 * t8], pv[2 * t8 + 1]);
      wrd[t8] = __builtin_bit_cast(unsigned int, hp);
    }
#pragma unroll
    for (int t8 = 0; t8 < 8; ++t8) owd[t8] = (unsigned int)__shfl_xor((int)wrd[t8], 32);
    const bool hb = (h != 0);
    __builtin_amdgcn_s_setprio(1);
#pragma unroll
    for (int kvb = 0; kvb < 2; ++kvb) {
      union { unsigned int u[4]; h8 v; } pb;
      pb.u[0] = hb ? owd[4 * kvb + 2] : wrd[4 * kvb + 0];
      pb.u[1] = hb ? owd[4 * kvb + 3] : wrd[4 * kvb + 1];
      pb.u[2] = hb ? wrd[4 * kvb + 2] : owd[4 * kvb + 0];
      pb.u[3] = hb ? wrd[4 * kvb + 3] : owd[4 * kvb + 1];
#pragma unroll
      for (int dt = 0; dt < 4; ++dt)
        o_acc[dt] = __builtin_amdgcn_mfma_f32_32x32x16_f16(vf[dt * 2 + kvb], pb.v, o_acc[dt], 0, 0, 0);
    }
    __builtin_amdgcn_s_setprio(0);
  }

  // ---- merge the 4 kv streams, normalize, transpose, store ----
  __syncthreads();
  float* MB = (float*)lds_raw;                 // [3 si][2 wq][64 row][64 lane] floats
  float* ML = (float*)(lds_raw + 98304);       // [3 si][2 wq][m 32 | l 32]
  if (wk >= 1) {
    int si = wk - 1;
#pragma unroll
    for (int dt = 0; dt < 4; ++dt)
#pragma unroll
      for (int rg = 0; rg < 16; ++rg)
        MB[(((si * 2 + wq) * 64) + dt * 16 + rg) * 64 + lane] = o_acc[dt][rg];
    if (lane < 32) {
      ML[(si * 2 + wq) * 64 + lane] = mcur;
      ML[(si * 2 + wq) * 64 + 32 + lane] = lsum;
    }
  }
  __syncthreads();
  if (wk == 0) {
#pragma unroll
    for (int si = 0; si < 3; ++si) {
      float m1 = ML[(si * 2 + wq) * 64 + r32];
      float l1 = ML[(si * 2 + wq) * 64 + 32 + r32];
      float ms = fmaxf(mcur, m1);
      float f0 = exp2f((mcur - ms) * L2E), f1 = exp2f((m1 - ms) * L2E);
#pragma unroll
      for (int dt = 0; dt < 4; ++dt)
#pragma unroll
        for (int rg = 0; rg < 16; ++rg)
          o_acc[dt][rg] = o_acc[dt][rg] * f0 +
                          MB[(((si * 2 + wq) * 64) + dt * 16 + rg) * 64 + lane] * f1;
      lsum = lsum * f0 + l1 * f1;
      mcur = ms;
    }
    float inv = 1.0f / lsum;
#pragma unroll
    for (int dt = 0; dt < 4; ++dt) o_acc[dt] = o_acc[dt] * inv;
  }
  __syncthreads();
  float* OT = (float*)lds_raw;                 // [64 q][129] (stride 129: bank = (r32+d)%32)
  if (wk == 0) {
#pragma unroll
    for (int dt = 0; dt < 4; ++dt)
#pragma unroll
      for (int rg = 0; rg < 16; ++rg) {
        int d = dt * 32 + (rg & 3) + 8 * (rg >> 2) + 4 * h;
        OT[(wq * 32 + r32) * 129 + d] = o_acc[dt][rg];
      }
  }
  __syncthreads();
#pragma unroll
  for (int pi = 0; pi < 16; ++pi) {
    int idx = pi * 512 + tid;
    int qr = idx >> 7, c = idx & 127;
    out[(size_t)(b * 4096 + q0 + qr) * 128 + c] = OT[qr * 129 + c];
  }
}

// ---------------- launcher ----------------
extern "C" void kernel_launch(void* const* d_in, const int* in_sizes, int n_in,
                              void* d_out, int out_size, void* d_ws, size_t ws_size,
                              hipStream_t stream) {
  const float* x     = (const float*)d_in[0];
  const float* cosT  = (const float*)d_in[1];
  const float* sinT  = (const float*)d_in[2];
  const float* Wq    = (const float*)d_in[3];
  const float* Wk    = (const float*)d_in[4];
  const float* Wv    = (const float*)d_in[5];
  const float* gamma = (const float*)d_in[6];
  char* ws = (char*)d_ws;
  _Float16* xh = (_Float16*)(ws);                    // 33,554,432 B
  _Float16* WT = (_Float16*)(ws + 33554432);         //    786,432 B
  _Float16* Qh = (_Float16*)(ws + 34340864);         //  4,194,304 B
  _Float16* Kh = (_Float16*)(ws + 38535168);         //  4,194,304 B (fragment-major)
  _Float16* VT = (_Float16*)(ws + 42729472);         //  4,194,304 B (fragment-major)
  float* out = (float*)d_out;

  (void)hipFuncSetAttribute(reinterpret_cast<const void*>(k_attn),
                            hipFuncAttributeMaxDynamicSharedMemorySize, 131072);

  hipLaunchKernelGGL(k_cvt_x, dim3(8192), dim3(256), 0, stream, x, xh);
  hipLaunchKernelGGL(k_cvt_w, dim3(1536), dim3(256), 0, stream, Wq, Wk, Wv, WT);
  hipLaunchKernelGGL(k_proj, dim3(384), dim3(256), 0, stream, xh, WT, cosT, sinT, gamma, Qh, Kh, VT);
  hipLaunchKernelGGL(k_attn, dim3(256), dim3(512), 131072, stream, Qh, Kh, VT, out);
}

// Round 6
// 110.614 us; speedup vs baseline: 1.3639x; 1.0274x over previous
//
#include <hip/hip_runtime.h>

typedef _Float16 h8  __attribute__((ext_vector_type(8)));
typedef float f32x16 __attribute__((ext_vector_type(16)));

#define L2E 1.4426950408889634f

__device__ __forceinline__ void gll16(const void* g, void* l) {
  __builtin_amdgcn_global_load_lds((const __attribute__((address_space(1))) void*)g,
                                   (__attribute__((address_space(3))) void*)l, 16, 0, 0);
}

// ---------------- kernel 0: x (f32) -> xh (f16) ----------------
__global__ void k_cvt_x(const float* __restrict__ x, _Float16* __restrict__ xh) {
  int i = (blockIdx.x * 256 + threadIdx.x) * 8;
  float4 a = *(const float4*)(x + i);
  float4 b = *(const float4*)(x + i + 4);
  h8 o;
  o[0] = (_Float16)a.x; o[1] = (_Float16)a.y; o[2] = (_Float16)a.z; o[3] = (_Float16)a.w;
  o[4] = (_Float16)b.x; o[5] = (_Float16)b.y; o[6] = (_Float16)b.z; o[7] = (_Float16)b.w;
  *(h8*)(xh + i) = o;
}

// ---------------- kernel 0b: W (1024x128 f32) -> WT (3x128x1024 f16) ------
__global__ void k_cvt_w(const float* __restrict__ Wq, const float* __restrict__ Wk,
                        const float* __restrict__ Wv, _Float16* __restrict__ WT) {
  int id = blockIdx.x * 256 + threadIdx.x;     // 0 .. 3*131072-1
  int mat = id >> 17;
  int rem = id & 131071;
  int k = rem >> 7;
  int c = rem & 127;
  const float* W = (mat == 0) ? Wq : ((mat == 1) ? Wk : Wv);
  WT[mat * 131072 + c * 1024 + k] = (_Float16)W[rem];
}

// ---------------- kernel 1: QKV projection + rotary + gate ----------------
// grid = 128 row-tiles * 3 matrices; 256 threads (4 waves of 2x2 over 128x128)
// Q: row-major [16384][128].
// K: fragment-major for mfma_32x32x16 A-operand:
//    half-index = (kv>>5)*4096 + (d>>4)*512 + ((d>>3)&1)*256 + (kv&31)*8 + (d&7)
// V: fragment-major (A-operand of PV, rows = d, k-dim = kv):
//    half-index = (kv>>5)*4096 + ((d>>5)*2 + ((kv>>4)&1))*512 + ((kv>>3)&1)*256 + (d&31)*8 + (kv&7)
__global__ __launch_bounds__(256, 2) void k_proj(
    const _Float16* __restrict__ xh,   // [16384][1024]
    const _Float16* __restrict__ WT,   // [3][128][1024]
    const float* __restrict__ cosT, const float* __restrict__ sinT,  // [4096][64]
    const float* __restrict__ gamma,
    _Float16* __restrict__ Qh, _Float16* __restrict__ Kh, _Float16* __restrict__ VT) {
  __shared__ __align__(16) unsigned char lds[65536];  // [2 phase][x 16KB | w 16KB]
  const int tid = threadIdx.x;
  const int rt  = blockIdx.x & 127;
  const int mat = blockIdx.x >> 7;
  const int w = tid >> 6, lane = tid & 63;
  const int wr = w >> 1, wc = w & 1;
  const int r32 = lane & 31, h = lane >> 5;
  const int row0 = rt * 128;
  const _Float16* Wbase = WT + mat * 131072;

  auto stage = [&](int j) {
    int k0 = j * 64;
    unsigned char* xb = lds + (j & 1) * 32768;
    unsigned char* wb = xb + 16384;
#pragma unroll
    for (int ii = 0; ii < 4; ++ii) {
      int off = ii * 4096 + tid * 16;
      int r = off >> 7;            // row in tile (128B rows)
      int c = (off >> 4) & 7;      // 16B chunk slot
      gll16(xh + (size_t)(row0 + r) * 1024 + k0 + ((c ^ (r & 7)) * 8), xb + off);
    }
#pragma unroll
    for (int ii = 0; ii < 4; ++ii) {
      int off = ii * 4096 + tid * 16;
      int r = off >> 7;
      int c = (off >> 4) & 7;
      gll16(Wbase + (size_t)r * 1024 + k0 + ((c ^ (r & 7)) * 8), wb + off);
    }
  };

  f32x16 acc[2][2];
#pragma unroll
  for (int a_ = 0; a_ < 2; ++a_)
#pragma unroll
    for (int b_ = 0; b_ < 2; ++b_)
#pragma unroll
      for (int r = 0; r < 16; ++r) acc[a_][b_][r] = 0.f;

  stage(0);
  for (int j = 0; j < 16; ++j) {
    if (j < 15) {
      stage(j + 1);
      asm volatile("s_waitcnt vmcnt(8)\n\ts_barrier" ::: "memory");
    } else {
      asm volatile("s_waitcnt vmcnt(0)\n\ts_barrier" ::: "memory");
    }
    const _Float16* xt = (const _Float16*)(lds + (j & 1) * 32768);
    const _Float16* wt = xt + 8192;
#pragma unroll
    for (int kk = 0; kk < 4; ++kk) {
      h8 a0, a1, b0, b1;
      { int r = wr * 64 + r32;      a0 = *(const h8*)(xt + r * 64 + (((kk * 2 + h) ^ (r & 7)) * 8)); }
      { int r = wr * 64 + 32 + r32; a1 = *(const h8*)(xt + r * 64 + (((kk * 2 + h) ^ (r & 7)) * 8)); }
      { int r = wc * 64 + r32;      b0 = *(const h8*)(wt + r * 64 + (((kk * 2 + h) ^ (r & 7)) * 8)); }
      { int r = wc * 64 + 32 + r32; b1 = *(const h8*)(wt + r * 64 + (((kk * 2 + h) ^ (r & 7)) * 8)); }
      acc[0][0] = __builtin_amdgcn_mfma_f32_32x32x16_f16(a0, b0, acc[0][0], 0, 0, 0);
      acc[0][1] = __builtin_amdgcn_mfma_f32_32x32x16_f16(a0, b1, acc[0][1], 0, 0, 0);
      acc[1][0] = __builtin_amdgcn_mfma_f32_32x32x16_f16(a1, b0, acc[1][0], 0, 0, 0);
      acc[1][1] = __builtin_amdgcn_mfma_f32_32x32x16_f16(a1, b1, acc[1][1], 0, 0, 0);
    }
    asm volatile("s_waitcnt lgkmcnt(0)\n\ts_barrier" ::: "memory");
  }

#pragma unroll
  for (int mt = 0; mt < 2; ++mt)
#pragma unroll
    for (int nt = 0; nt < 2; ++nt) {
      int col = wc * 64 + nt * 32 + r32;
      f32x16 c = acc[mt][nt];
      if (mat < 2) {
        float ge = expf(gamma[col]);
        float sc = (mat == 0) ? ge * 0.08838834764831845f : ge;  // fold 1/sqrt(128) into Q
        int i2 = col >> 1;
#pragma unroll
        for (int rg = 0; rg < 16; ++rg) {
          int row = row0 + wr * 64 + mt * 32 + (rg & 3) + 8 * (rg >> 2) + 4 * h;
          int pos = row & 4095;
          float cv = cosT[pos * 64 + i2], sv = sinT[pos * 64 + i2];
          float val = c[rg];
          float ot = __shfl_xor(val, 1);
          // even d: t1*cos - t2*sin ; odd d: t1*sin + t2*cos
          float rr = (lane & 1) ? fmaf(val, cv, ot * sv) : fmaf(val, cv, -ot * sv);
          float v = rr * sc;
          if (mat == 0) {
            Qh[(size_t)row * 128 + col] = (_Float16)v;
          } else {
            size_t ka = (size_t)(row >> 5) * 4096 + (col >> 4) * 512 +
                        ((col >> 3) & 1) * 256 + (row & 31) * 8 + (col & 7);
            Kh[ka] = (_Float16)v;
          }
        }
      } else {
        // V fragment-major: rg group g covers 4 consecutive kv at fixed d=col.
#pragma unroll
        for (int g = 0; g < 4; ++g) {
          union { _Float16 hh[4]; uint2 u; } pk;
#pragma unroll
          for (int j2 = 0; j2 < 4; ++j2) pk.hh[j2] = (_Float16)c[g * 4 + j2];
          int kv = row0 + wr * 64 + mt * 32 + 8 * g + 4 * h;  // multiple of 4
          size_t va = (size_t)(kv >> 5) * 4096 +
                      ((col >> 5) * 2 + ((kv >> 4) & 1)) * 512 +
                      ((kv >> 3) & 1) * 256 + (col & 31) * 8 + (kv & 7);
          *(uint2*)(VT + va) = pk.u;
        }
      }
    }
}

// ---------------- kernel 2: flash attention (no-LDS, software-pipelined) ----
// grid = B*64 blocks, 512 threads = 8 waves: wk = kv stream (0..3), wq = q tile (0/1)
// 2-stage pipeline: QK(i+1) issues before softmax(i)+PV(i) so the MFMA pipe
// overlaps the VALU softmax chain. No barriers in the main loop (nothing shared).
__global__ __launch_bounds__(512, 2) void k_attn(
    const _Float16* __restrict__ Qh, const _Float16* __restrict__ Kh,
    const _Float16* __restrict__ VT, float* __restrict__ out) {
  extern __shared__ __align__(16) unsigned char lds_raw[];
  const int tid = threadIdx.x;
  const int bid = blockIdx.x;
  const int xcd = bid & 7;
  const int b  = xcd >> 1;
  const int q0 = ((xcd & 1) + 2 * (bid >> 3)) * 64;
  const int w = tid >> 6, lane = tid & 63;
  const int wk = w >> 1, wq = w & 1;
  const int r32 = lane & 31, h = lane >> 5;

  // Q fragments in registers (B-operand of swapped QK^T)
  const _Float16* qrow = Qh + (size_t)(b * 4096 + q0 + wq * 32 + r32) * 128;
  h8 qf[8];
#pragma unroll
  for (int kk = 0; kk < 8; ++kk) qf[kk] = *(const h8*)(qrow + kk * 16 + h * 8);

  // fragment bases for this wave's stream (tiles t = b*128 + 4*i + wk)
  const _Float16* Kfb = Kh + (size_t)(b * 128 + wk) * 4096 + lane * 8;
  const _Float16* Vfb = VT + (size_t)(b * 128 + wk) * 4096 + lane * 8;

  f32x16 o_acc[4];
#pragma unroll
  for (int dt = 0; dt < 4; ++dt)
#pragma unroll
    for (int r = 0; r < 16; ++r) o_acc[dt][r] = 0.f;
  float mcur = -INFINITY, lsum = 0.f;

  // prologue: K(0) -> kf; st_cur = QK(0); kf <- K(1)
  h8 kf[8];
#pragma unroll
  for (int kk = 0; kk < 8; ++kk) kf[kk] = *(const h8*)(Kfb + kk * 512);
  f32x16 st_cur;
#pragma unroll
  for (int r = 0; r < 16; ++r) st_cur[r] = 0.f;
#pragma unroll
  for (int kk = 0; kk < 8; ++kk) {
    h8 a = kf[kk];
    kf[kk] = *(const h8*)(Kfb + 16384 + kk * 512);
    st_cur = __builtin_amdgcn_mfma_f32_32x32x16_f16(a, qf[kk], st_cur, 0, 0, 0);
  }

  for (int i = 0; i < 32; ++i) {
    // V fragments for tile i (consumed by PV at the end of this iteration)
    const _Float16* Vcur = Vfb + (size_t)i * 16384;
    h8 vf[8];
#pragma unroll
    for (int u = 0; u < 8; ++u) vf[u] = *(const h8*)(Vcur + u * 512);

    // QK for tile i+1 (result not consumed until next iteration -> overlaps
    // with softmax below); roll-refill kf for tile i+2
    f32x16 st_next;
#pragma unroll
    for (int r = 0; r < 16; ++r) st_next[r] = 0.f;
    if (i < 31) {
      const _Float16* Kn2 = Kfb + (size_t)(i + 2 < 32 ? i + 2 : 31) * 16384;
      __builtin_amdgcn_s_setprio(1);
#pragma unroll
      for (int kk = 0; kk < 8; ++kk) {
        h8 a = kf[kk];
        kf[kk] = *(const h8*)(Kn2 + kk * 512);
        st_next = __builtin_amdgcn_mfma_f32_32x32x16_f16(a, qf[kk], st_next, 0, 0, 0);
      }
      __builtin_amdgcn_s_setprio(0);
    }

    // online softmax on st_cur (per lane = one q row; partner half in lane^32)
    f32x16 st = st_cur;
    float pm = fmaxf(fmaxf(fmaxf(st[0], st[1]), fmaxf(st[2], st[3])),
                     fmaxf(fmaxf(st[4], st[5]), fmaxf(st[6], st[7])));
    float pm2 = fmaxf(fmaxf(fmaxf(st[8], st[9]), fmaxf(st[10], st[11])),
                      fmaxf(fmaxf(st[12], st[13]), fmaxf(st[14], st[15])));
    pm = fmaxf(pm, pm2);
    pm = fmaxf(pm, __shfl_xor(pm, 32));
    // defer-max: only rescale when the running max grew by > 8
    if (!__all(pm - mcur <= 8.0f)) {
      float mnew = fmaxf(mcur, pm);
      float fsc = exp2f((mcur - mnew) * L2E);
      lsum *= fsc;
#pragma unroll
      for (int dt = 0; dt < 4; ++dt) o_acc[dt] = o_acc[dt] * fsc;
      mcur = mnew;
    }
    float mn2 = mcur * L2E;
    float pv[16]; float ps = 0.f;
#pragma unroll
    for (int r = 0; r < 16; ++r) { pv[r] = exp2f(fmaf(st[r], L2E, -mn2)); ps += pv[r]; }
    ps += __shfl_xor(ps, 32);
    lsum += ps;

    // pack P to half2 words; kv pair of word t (own half h): 8*(t>>1) + 4h + 2*(t&1)
    unsigned int wrd[8], owd[8];
#pragma unroll
    for (int t8 = 0; t8 < 8; ++t8) {
      auto hp = __builtin_amdgcn_cvt_pkrtz(pv[2 * t8], pv[2 * t8 + 1]);
      wrd[t8] = __builtin_bit_cast(unsigned int, hp);
    }
#pragma unroll
    for (int t8 = 0; t8 < 8; ++t8) owd[t8] = (unsigned int)__shfl_xor((int)wrd[t8], 32);
    const bool hb = (h != 0);
    __builtin_amdgcn_s_setprio(1);
#pragma unroll
    for (int kvb = 0; kvb < 2; ++kvb) {
      union { unsigned int u[4]; h8 v; } pb;
      pb.u[0] = hb ? owd[4 * kvb + 2] : wrd[4 * kvb + 0];
      pb.u[1] = hb ? owd[4 * kvb + 3] : wrd[4 * kvb + 1];
      pb.u[2] = hb ? wrd[4 * kvb + 2] : owd[4 * kvb + 0];
      pb.u[3] = hb ? wrd[4 * kvb + 3] : owd[4 * kvb + 1];
#pragma unroll
      for (int dt = 0; dt < 4; ++dt)
        o_acc[dt] = __builtin_amdgcn_mfma_f32_32x32x16_f16(vf[dt * 2 + kvb], pb.v, o_acc[dt], 0, 0, 0);
    }
    __builtin_amdgcn_s_setprio(0);
    st_cur = st_next;
  }

  // ---- merge the 4 kv streams, normalize, transpose, store ----
  __syncthreads();
  float* MB = (float*)lds_raw;                 // [3 si][2 wq][64 row][64 lane] floats
  float* ML = (float*)(lds_raw + 98304);       // [3 si][2 wq][m 32 | l 32]
  if (wk >= 1) {
    int si = wk - 1;
#pragma unroll
    for (int dt = 0; dt < 4; ++dt)
#pragma unroll
      for (int rg = 0; rg < 16; ++rg)
        MB[(((si * 2 + wq) * 64) + dt * 16 + rg) * 64 + lane] = o_acc[dt][rg];
    if (lane < 32) {
      ML[(si * 2 + wq) * 64 + lane] = mcur;
      ML[(si * 2 + wq) * 64 + 32 + lane] = lsum;
    }
  }
  __syncthreads();
  if (wk == 0) {
#pragma unroll
    for (int si = 0; si < 3; ++si) {
      float m1 = ML[(si * 2 + wq) * 64 + r32];
      float l1 = ML[(si * 2 + wq) * 64 + 32 + r32];
      float ms = fmaxf(mcur, m1);
      float f0 = exp2f((mcur - ms) * L2E), f1 = exp2f((m1 - ms) * L2E);
#pragma unroll
      for (int dt = 0; dt < 4; ++dt)
#pragma unroll
        for (int rg = 0; rg < 16; ++rg)
          o_acc[dt][rg] = o_acc[dt][rg] * f0 +
                          MB[(((si * 2 + wq) * 64) + dt * 16 + rg) * 64 + lane] * f1;
      lsum = lsum * f0 + l1 * f1;
      mcur = ms;
    }
    float inv = 1.0f / lsum;
#pragma unroll
    for (int dt = 0; dt < 4; ++dt) o_acc[dt] = o_acc[dt] * inv;
  }
  __syncthreads();
  float* OT = (float*)lds_raw;                 // [64 q][129] (stride 129: bank = (r32+d)%32)
  if (wk == 0) {
#pragma unroll
    for (int dt = 0; dt < 4; ++dt)
#pragma unroll
      for (int rg = 0; rg < 16; ++rg) {
        int d = dt * 32 + (rg & 3) + 8 * (rg >> 2) + 4 * h;
        OT[(wq * 32 + r32) * 129 + d] = o_acc[dt][rg];
      }
  }
  __syncthreads();
#pragma unroll
  for (int pi = 0; pi < 16; ++pi) {
    int idx = pi * 512 + tid;
    int qr = idx >> 7, c = idx & 127;
    out[(size_t)(b * 4096 + q0 + qr) * 128 + c] = OT[qr * 129 + c];
  }
}

// ---------------- launcher ----------------
extern "C" void kernel_launch(void* const* d_in, const int* in_sizes, int n_in,
                              void* d_out, int out_size, void* d_ws, size_t ws_size,
                              hipStream_t stream) {
  const float* x     = (const float*)d_in[0];
  const float* cosT  = (const float*)d_in[1];
  const float* sinT  = (const float*)d_in[2];
  const float* Wq    = (const float*)d_in[3];
  const float* Wk    = (const float*)d_in[4];
  const float* Wv    = (const float*)d_in[5];
  const float* gamma = (const float*)d_in[6];
  char* ws = (char*)d_ws;
  _Float16* xh = (_Float16*)(ws);                    // 33,554,432 B
  _Float16* WT = (_Float16*)(ws + 33554432);         //    786,432 B
  _Float16* Qh = (_Float16*)(ws + 34340864);         //  4,194,304 B
  _Float16* Kh = (_Float16*)(ws + 38535168);         //  4,194,304 B (fragment-major)
  _Float16* VT = (_Float16*)(ws + 42729472);         //  4,194,304 B (fragment-major)
  float* out = (float*)d_out;

  (void)hipFuncSetAttribute(reinterpret_cast<const void*>(k_attn),
                            hipFuncAttributeMaxDynamicSharedMemorySize, 131072);

  hipLaunchKernelGGL(k_cvt_x, dim3(8192), dim3(256), 0, stream, x, xh);
  hipLaunchKernelGGL(k_cvt_w, dim3(1536), dim3(256), 0, stream, Wq, Wk, Wv, WT);
  hipLaunchKernelGGL(k_proj, dim3(384), dim3(256), 0, stream, xh, WT, cosT, sinT, gamma, Qh, Kh, VT);
  hipLaunchKernelGGL(k_attn, dim3(256), dim3(512), 131072, stream, Qh, Kh, VT, out);
}